// Round 1
// baseline (694.191 us; speedup 1.0000x reference)
//
#include <hip/hip_runtime.h>

// GRU: B=4096, T=512, I=32, H=64. One WG per 16-batch tile, 4 waves.
// Wave w owns hidden slice [w*16, w*16+16) for all 3 gates.
// GEMM orientation: hp^T = W_hh * h^T  (A = weight rows in registers,
// B = h^T from LDS, one b128 read per K-chunk, one b64 write per step).

#define TSTEPS 512
#define IDIM 32
#define HDIM 64

typedef __bf16 bf16x8 __attribute__((ext_vector_type(8)));
typedef __bf16 bf16x4 __attribute__((ext_vector_type(4)));
typedef float f32x4 __attribute__((ext_vector_type(4)));

__device__ __forceinline__ float fast_sigmoid(float x) {
    return __builtin_amdgcn_rcpf(1.0f + __expf(-x));
}
__device__ __forceinline__ float fast_tanh(float x) {
    // tanh(x) = 1 - 2/(1+e^{2x}); exp overflow -> inf -> rcp -> 0 (correct limit)
    return 1.0f - 2.0f * __builtin_amdgcn_rcpf(1.0f + __expf(2.0f * x));
}

__global__ __launch_bounds__(256) void gru_fused_kernel(
    const float* __restrict__ seq, const float* __restrict__ W_ih,
    const float* __restrict__ W_hh, const float* __restrict__ b_ih,
    const float* __restrict__ b_hh, float* __restrict__ out)
{
    // h^T in bf16, double-buffered. Row = batch (16), col = hidden k (64, pad to 72).
    // stride 144 B keeps 16 B alignment for b128 reads.
    __shared__ __bf16 hB[2][16][72];

    const int tid  = threadIdx.x;
    const int w    = tid >> 6;        // wave id 0..3 -> hidden slice
    const int lane = tid & 63;
    const int l    = lane & 15;       // batch col within tile / A row within 16-tile
    const int q    = lane >> 4;       // quad -> k offset q*8
    const int b0   = blockIdx.x * 16;

    // zero-init h (t=0 reads buffer 0; init both for safety)
    for (int i = tid; i < 2 * 16 * 72; i += 256)
        (&hB[0][0][0])[i] = (__bf16)0.0f;

    // ---- loop-invariant A-fragments (weights), bf16 ----
    // A[m][k]: m = lane&15 -> gate row g*64 + w*16 + l ; k = kc*32 + q*8 + j
    bf16x8 aH[3][2];  // [gate r/z/n][k-chunk]
    bf16x8 aI[3];     // input weights, K=32 (one chunk)
    #pragma unroll
    for (int g = 0; g < 3; ++g) {
        const int row = g * 64 + w * 16 + l;
        #pragma unroll
        for (int kc = 0; kc < 2; ++kc) {
            const float* p = W_hh + row * HDIM + kc * 32 + q * 8;
            #pragma unroll
            for (int j = 0; j < 8; ++j) aH[g][kc][j] = (__bf16)p[j];
        }
        const float* pi = W_ih + row * IDIM + q * 8;
        #pragma unroll
        for (int j = 0; j < 8; ++j) aI[g][j] = (__bf16)pi[j];
    }

    // ---- biases at this lane's C/D rows: hidden offset = w*16 + 4q + reg ----
    float biasR[4], biasZ[4], biasIN[4], biasHN[4];
    #pragma unroll
    for (int r = 0; r < 4; ++r) {
        const int g = w * 16 + 4 * q + r;
        biasR[r]  = b_ih[g]       + b_hh[g];
        biasZ[r]  = b_ih[64 + g]  + b_hh[64 + g];
        biasIN[r] = b_ih[128 + g];          // n-gate: keep separate, r scales hn only
        biasHN[r] = b_hh[128 + g];
    }

    float h[4] = {0.f, 0.f, 0.f, 0.f};  // fp32 h at this lane's C/D positions

    // seq row for B-operand of input proj: B[k][n] = seq[b0+l][t][k], k = q*8+j
    const float* seqRow = seq + ((size_t)(b0 + l) * TSTEPS) * IDIM + q * 8;
    float4 nx0 = *(const float4*)(seqRow);
    float4 nx1 = *(const float4*)(seqRow + 4);

    __syncthreads();

    const f32x4 zero4 = {0.f, 0.f, 0.f, 0.f};

    for (int t = 0; t < TSTEPS; ++t) {
        const int buf = t & 1;

        float x[8];
        x[0] = nx0.x; x[1] = nx0.y; x[2] = nx0.z; x[3] = nx0.w;
        x[4] = nx1.x; x[5] = nx1.y; x[6] = nx1.z; x[7] = nx1.w;
        // prefetch next timestep (independent of h chain -> hides HBM latency)
        if (t + 1 < TSTEPS) {
            const float* pn = seqRow + (size_t)(t + 1) * IDIM;
            nx0 = *(const float4*)(pn);
            nx1 = *(const float4*)(pn + 4);
        }

        bf16x8 xb;
        #pragma unroll
        for (int j = 0; j < 8; ++j) xb[j] = (__bf16)x[j];

        // B-fragments of h^T (written by all waves last step; barrier below ordered it)
        bf16x8 hb0 = *(const bf16x8*)&hB[buf][l][q * 8];
        bf16x8 hb1 = *(const bf16x8*)&hB[buf][l][32 + q * 8];

        f32x4 accR  = __builtin_amdgcn_mfma_f32_16x16x32_bf16(aI[0], xb, zero4, 0, 0, 0);
        f32x4 accZ  = __builtin_amdgcn_mfma_f32_16x16x32_bf16(aI[1], xb, zero4, 0, 0, 0);
        f32x4 accXN = __builtin_amdgcn_mfma_f32_16x16x32_bf16(aI[2], xb, zero4, 0, 0, 0);
        accR  = __builtin_amdgcn_mfma_f32_16x16x32_bf16(aH[0][0], hb0, accR, 0, 0, 0);
        accR  = __builtin_amdgcn_mfma_f32_16x16x32_bf16(aH[0][1], hb1, accR, 0, 0, 0);
        accZ  = __builtin_amdgcn_mfma_f32_16x16x32_bf16(aH[1][0], hb0, accZ, 0, 0, 0);
        accZ  = __builtin_amdgcn_mfma_f32_16x16x32_bf16(aH[1][1], hb1, accZ, 0, 0, 0);
        f32x4 accHN = __builtin_amdgcn_mfma_f32_16x16x32_bf16(aH[2][0], hb0, zero4, 0, 0, 0);
        accHN = __builtin_amdgcn_mfma_f32_16x16x32_bf16(aH[2][1], hb1, accHN, 0, 0, 0);

        bf16x4 hOut;
        #pragma unroll
        for (int r = 0; r < 4; ++r) {
            const float rg = fast_sigmoid(accR[r] + biasR[r]);
            const float zg = fast_sigmoid(accZ[r] + biasZ[r]);
            const float ng = fast_tanh(accXN[r] + biasIN[r] + rg * (accHN[r] + biasHN[r]));
            h[r] = ng + zg * (h[r] - ng);
            hOut[r] = (__bf16)h[r];
        }
        // 4 consecutive hidden indices (w*16+4q .. +3) for batch l -> one 8B write
        *(bf16x4*)&hB[buf ^ 1][l][w * 16 + 4 * q] = hOut;
        __syncthreads();
    }

    // out[b][k], k = w*16 + 4q + reg : 4 consecutive floats
    float4 o = {h[0], h[1], h[2], h[3]};
    *(float4*)&out[(size_t)(b0 + l) * HDIM + w * 16 + 4 * q] = o;
}

extern "C" void kernel_launch(void* const* d_in, const int* in_sizes, int n_in,
                              void* d_out, int out_size, void* d_ws, size_t ws_size,
                              hipStream_t stream) {
    const float* seq  = (const float*)d_in[0];
    const float* W_ih = (const float*)d_in[1];
    const float* W_hh = (const float*)d_in[2];
    const float* b_ih = (const float*)d_in[3];
    const float* b_hh = (const float*)d_in[4];
    float* out = (float*)d_out;
    // 4096 batches / 16 per WG = 256 workgroups (1 per CU)
    gru_fused_kernel<<<256, 256, 0, stream>>>(seq, W_ih, W_hh, b_ih, b_hh, out);
}